// Round 19
// baseline (239.165 us; speedup 1.0000x reference)
//
#include <hip/hip_runtime.h>
#include <hip/hip_bf16.h>

#define NN 20000
#define EE 640000
#define PQ_ALLOC 1049600   // padded CSR capacity (uints): >= E + 15*N + slack; 1025*1024

typedef __attribute__((ext_vector_type(8))) short bf16x8;
typedef __attribute__((ext_vector_type(4))) float f32x4;
typedef __attribute__((ext_vector_type(2))) float f32x2;

__device__ __forceinline__ ushort f2b(float f) {
    __hip_bfloat16 h = __float2bfloat16(f);
    return *(ushort*)&h;
}
__device__ __forceinline__ float b2f(ushort u) {
    __hip_bfloat16 h = *(__hip_bfloat16*)&u;
    return __bfloat162float(h);
}

// accumulate 8 bf16 feats scaled by m into 4 packed f32x2 accs (v_pk_fma_f32)
__device__ __forceinline__ void acc8p(float m, bf16x8 v, f32x2* acc) {
    union { bf16x8 v; unsigned u[4]; } t;
    t.v = v;
    f32x2 mm = {m, m};
    #pragma unroll
    for (int k = 0; k < 4; ++k) {
        f32x2 f = { __uint_as_float(t.u[k] << 16),
                    __uint_as_float(t.u[k] & 0xffff0000u) };
        acc[k] = __builtin_elementwise_fma(mm, f, acc[k]);
    }
}

// async global->LDS, 16B per lane. LDS dest = wave-uniform base + lane*16.
__device__ __forceinline__ void gload16(const ushort* g, ushort* l) {
    __builtin_amdgcn_global_load_lds(
        (const __attribute__((address_space(1))) void*)g,
        (__attribute__((address_space(3))) void*)l, 16, 0, 0);
}

// ---------------- CSR build ----------------

__global__ void hist_kernel(const int* __restrict__ col, int* __restrict__ cnt, int e) {
    int i = blockIdx.x * 256 + threadIdx.x;
    if (i < e) atomicAdd(&cnt[col[i]], 1);
}

__device__ __forceinline__ int block_exscan(int v) {
    __shared__ int wsum[4];
    int tid = threadIdx.x, lane = tid & 63, w = tid >> 6;
    int x = v;
    #pragma unroll
    for (int d = 1; d < 64; d <<= 1) {
        int y = __shfl_up(x, d, 64);
        if (lane >= d) x += y;
    }
    if (lane == 63) wsum[w] = x;
    __syncthreads();
    if (tid == 0) {
        int s = 0;
        #pragma unroll
        for (int k = 0; k < 4; ++k) { int t = wsum[k]; wsum[k] = s; s += t; }
    }
    __syncthreads();
    return wsum[w] + x - v;
}

// scan phase 1 (over counts PADDED to x16) + dinv fused
__global__ __launch_bounds__(256) void scan_p1_kernel(const int* __restrict__ cnt,
                                                      int* __restrict__ offs,
                                                      int* __restrict__ bsum,
                                                      float* __restrict__ dinv, int n) {
    int i = blockIdx.x * 256 + threadIdx.x;
    int v = (i < n) ? cnt[i] : 0;
    int vpad = (v + 15) & ~15;
    int e = block_exscan(vpad);
    if (i < n) {
        offs[i] = e;
        dinv[i] = rsqrtf((float)(v + 1));   // +1 self-loop; always > 0
    }
    if (threadIdx.x == 255) bsum[blockIdx.x] = e + vpad;
}

// merged phases 2+3: each block locally scans bsum (nblk <= 256) and applies its base
__global__ __launch_bounds__(256) void scan_p23_kernel(int* __restrict__ offs,
                                                       const int* __restrict__ bsum,
                                                       int* __restrict__ cursor,
                                                       int n, int nblk) {
    __shared__ int base_s;
    int t = threadIdx.x;
    int v = (t < nblk) ? bsum[t] : 0;
    int e = block_exscan(v);
    if (t == blockIdx.x) base_s = e;
    __syncthreads();
    int i = blockIdx.x * 256 + t;
    if (i < n) {
        int o = offs[i] + base_s;
        offs[i] = o;
        cursor[i] = o;
    }
}

// pack: hi16 = bf16(norm), lo16 = src id (n < 65536). Pad slots stay 0 (pre-zeroed).
__global__ void scatter_kernel(const int* __restrict__ row, const int* __restrict__ col,
                               const float* __restrict__ dinv, int* __restrict__ cursor,
                               unsigned* __restrict__ pq, int e) {
    int i = blockIdx.x * 256 + threadIdx.x;
    if (i >= e) return;
    int s = row[i], d = col[i];
    int pos = atomicAdd(&cursor[d], 1);
    unsigned nb = f2b(dinv[s] * dinv[d]);
    pq[pos] = (nb << 16) | (unsigned)s;
}

// ---------------- fused prep: wprep x3 + x->bf16 + out=bout + cnt=0 + pq=0 ----------------
__global__ __launch_bounds__(256) void prep_kernel(
    const float* __restrict__ W1, const float* __restrict__ Wh,
    const float* __restrict__ W2, ushort* __restrict__ Wt,
    const float* __restrict__ x, ushort* __restrict__ xb,
    const float* __restrict__ bout, float* __restrict__ outv,
    int* __restrict__ cnt, unsigned* __restrict__ pq, int n) {
    int bid = blockIdx.x;
    if (bid < 768) {
        const float* W = (bid < 256) ? W1 : ((bid < 512) ? Wh : W2);
        ushort* dst = Wt + (size_t)(bid >> 8) * 256 * 512;
        int col = bid & 255;
        #pragma unroll
        for (int kv = threadIdx.x; kv < 512; kv += 256) {
            int k = kv & 255;
            float w = W[(size_t)k * 256 + col];
            ushort hi = f2b(w);
            dst[(size_t)col * 512 + kv] = (kv < 256) ? hi : f2b(w - b2f(hi));
        }
    } else if (bid < 768 + 2500) {
        int i = (bid - 768) * 256 + threadIdx.x;   // per 8 elems, total n*32
        if (i < n * 32) {
            float4 a = ((const float4*)x)[2 * i];
            float4 b = ((const float4*)x)[2 * i + 1];
            union { bf16x8 v; ushort s[8]; } o;
            o.s[0] = f2b(a.x); o.s[1] = f2b(a.y); o.s[2] = f2b(a.z); o.s[3] = f2b(a.w);
            o.s[4] = f2b(b.x); o.s[5] = f2b(b.y); o.s[6] = f2b(b.z); o.s[7] = f2b(b.w);
            ((bf16x8*)xb)[i] = o.v;
        }
    } else if (bid < 768 + 2500 + 79) {
        int i = (bid - 3268) * 256 + threadIdx.x;
        if (i < n) outv[i] = bout[0];
    } else if (bid < 768 + 2500 + 79 + 79) {
        int i = (bid - 3347) * 256 + threadIdx.x;
        if (i < n) cnt[i] = 0;
    } else {
        int i = (bid - 3426) * 256 + threadIdx.x;   // uint4 zero-fill of pq
        uint4 z = {0u, 0u, 0u, 0u};
        ((uint4*)pq)[i] = z;                        // PQ_ALLOC/4 = 1025*256
    }
}

// ---------------- bf16 MFMA GEMM: G = A @ (W_hi + W_lo), real K=256, 4 kt ----------------
// Per kt: stage A (128x64) ONCE + B tile (128 rows: 0-63 = W_hi cols, 64-127 = W_lo cols).
// Each af used against both bf_hi and bf_lo into the same acc. LDS dbuf, vmcnt(8), XOR-swizzle.
__global__ __launch_bounds__(256) void gemm_mfma_kernel(
    const ushort* __restrict__ A, const ushort* __restrict__ Wt,
    ushort* __restrict__ G, int n) {
    __shared__ ushort Ast[2][128][64];
    __shared__ ushort Bst[2][128][64];
    int tid = threadIdx.x;
    int lane = tid & 63, wid = tid >> 6;
    int rowbase = blockIdx.x * 128;
    int colbase = blockIdx.y * 64;

    f32x4 zero = {0.f, 0.f, 0.f, 0.f};
    f32x4 acc[2][4];
    #pragma unroll
    for (int m = 0; m < 2; ++m)
        #pragma unroll
        for (int nn = 0; nn < 4; ++nn) acc[m][nn] = zero;

    int rsub = lane >> 3, sl = lane & 7;
    const ushort* asrc[4];
    const ushort* bsrc[4];
    #pragma unroll
    for (int q = 0; q < 4; ++q) {
        int rin = wid * 32 + q * 8 + rsub;      // 0..127
        int c = sl ^ (rin & 7);
        int gr = min(rowbase + rin, n - 1);
        asrc[q] = A + (size_t)gr * 256 + c * 8;
        int col_r = rin & 63;
        int part = rin >> 6;                    // 0 = hi, 1 = lo
        bsrc[q] = Wt + (size_t)(colbase + col_r) * 512 + part * 256 + c * 8;
    }

    auto stage = [&](int kt, int buf) {
        int kv0 = kt * 64;
        #pragma unroll
        for (int q = 0; q < 4; ++q)
            gload16(asrc[q] + kv0, &Ast[buf][wid * 32 + q * 8][0]);
        #pragma unroll
        for (int q = 0; q < 4; ++q)
            gload16(bsrc[q] + kv0, &Bst[buf][wid * 32 + q * 8][0]);
    };

    stage(0, 0);
    for (int kt = 0; kt < 4; ++kt) {
        int cur = kt & 1;
        if (kt < 3) {
            stage(kt + 1, cur ^ 1);
            asm volatile("s_waitcnt vmcnt(8)" ::: "memory");
        } else {
            asm volatile("s_waitcnt vmcnt(0)" ::: "memory");
        }
        __builtin_amdgcn_s_barrier();
        #pragma unroll
        for (int kk = 0; kk < 2; ++kk) {
            int clog = kk * 4 + (lane >> 4);
            bf16x8 af[2], bfh[4], bfl[4];
            #pragma unroll
            for (int m = 0; m < 2; ++m) {
                int row = wid * 32 + m * 16 + (lane & 15);
                af[m] = *(const bf16x8*)&Ast[cur][row][(clog ^ (row & 7)) * 8];
            }
            #pragma unroll
            for (int nn = 0; nn < 4; ++nn) {
                int rowh = nn * 16 + (lane & 15);
                int rowl = rowh + 64;
                bfh[nn] = *(const bf16x8*)&Bst[cur][rowh][(clog ^ (rowh & 7)) * 8];
                bfl[nn] = *(const bf16x8*)&Bst[cur][rowl][(clog ^ (rowl & 7)) * 8];
            }
            #pragma unroll
            for (int m = 0; m < 2; ++m)
                #pragma unroll
                for (int nn = 0; nn < 4; ++nn) {
                    acc[m][nn] = __builtin_amdgcn_mfma_f32_16x16x32_bf16(
                        af[m], bfh[nn], acc[m][nn], 0, 0, 0);
                    acc[m][nn] = __builtin_amdgcn_mfma_f32_16x16x32_bf16(
                        af[m], bfl[nn], acc[m][nn], 0, 0, 0);
                }
        }
        __builtin_amdgcn_s_barrier();
    }

    #pragma unroll
    for (int nn = 0; nn < 4; ++nn) {
        int col = colbase + nn * 16 + (lane & 15);
        #pragma unroll
        for (int m = 0; m < 2; ++m) {
            int grow0 = rowbase + wid * 32 + m * 16 + ((lane >> 4) << 2);
            f32x4 v = acc[m][nn];
            #pragma unroll
            for (int rr = 0; rr < 4; ++rr) {
                int row = grow0 + rr;
                if (row < n)
                    G[(size_t)row * 256 + col] = f2b(v[rr]);
            }
        }
    }
}

// ---------------- aggregation v13nt: padded CSR, predication-free, nt meta stream ----------------
// G bf16 [n][256]. chunk = bid&3 (slice 2.56MB, XCD-pinned). 4 waves x 2 nodes = 8 nodes/block.
// Lane: half = lane>>5 (node), esub = (lane>>3)&3 (4 edge slots), fsub = lane&7 (bf16x8).
// Segments padded to x16 with (norm=0, src=0) -> no compares/selects in the loop.
// Meta loads nontemporal: each XCD reads each pq line once per dispatch; keep slice in L2.
template<bool FINAL>
__global__ __launch_bounds__(256) void agg_kernel(
    const ushort* __restrict__ g,
    const int* __restrict__ offs, const int* __restrict__ cnt,
    const unsigned* __restrict__ pq,
    const float* __restrict__ dinv,
    const float* __restrict__ bias,
    ushort* __restrict__ hb,          // !FINAL
    float* __restrict__ h3,           // FINAL
    const float* __restrict__ Wout, float* __restrict__ outv,
    int n) {
    int chunk = blockIdx.x & 3;
    int lane = threadIdx.x & 63;
    int half = lane >> 5;
    int esub = (lane >> 3) & 3;
    int fsub = lane & 7;
    int node = (blockIdx.x >> 2) * 8 + (threadIdx.x >> 6) * 2 + half;  // n%8==0
    const ushort* base = g + chunk * 64 + fsub * 8;

    int beg = offs[node];
    int npad = (cnt[node] + 15) & ~15;
    const unsigned* pe = pq + beg + esub;
    f32x2 acc[4] = {};

    unsigned q0 = __builtin_nontemporal_load(pe);
    unsigned q1 = __builtin_nontemporal_load(pe + 4);
    unsigned q2 = __builtin_nontemporal_load(pe + 8);
    unsigned q3 = __builtin_nontemporal_load(pe + 12);

    for (int j = 0; j < npad; j += 16) {
        const unsigned* pn = pe + j + 16;      // prefetch (may overrun segment; never consumed)
        unsigned p0 = __builtin_nontemporal_load(pn);
        unsigned p1 = __builtin_nontemporal_load(pn + 4);
        unsigned p2 = __builtin_nontemporal_load(pn + 8);
        unsigned p3 = __builtin_nontemporal_load(pn + 12);

        float m0 = __uint_as_float(q0 & 0xffff0000u);
        float m1 = __uint_as_float(q1 & 0xffff0000u);
        float m2 = __uint_as_float(q2 & 0xffff0000u);
        float m3 = __uint_as_float(q3 & 0xffff0000u);
        bf16x8 v0 = *(const bf16x8*)(base + (size_t)(q0 & 0xffffu) * 256);
        bf16x8 v1 = *(const bf16x8*)(base + (size_t)(q1 & 0xffffu) * 256);
        bf16x8 v2 = *(const bf16x8*)(base + (size_t)(q2 & 0xffffu) * 256);
        bf16x8 v3 = *(const bf16x8*)(base + (size_t)(q3 & 0xffffu) * 256);
        acc8p(m0, v0, acc);
        acc8p(m1, v1, acc);
        acc8p(m2, v2, acc);
        acc8p(m3, v3, acc);
        q0 = p0; q1 = p1; q2 = p2; q3 = p3;
    }

    // reduce across the 4 esub groups within each 32-lane half
    #pragma unroll
    for (int d = 8; d < 32; d <<= 1)
        #pragma unroll
        for (int k = 0; k < 4; ++k) {
            acc[k][0] += __shfl_xor(acc[k][0], d, 64);
            acc[k][1] += __shfl_xor(acc[k][1], d, 64);
        }

    if (esub == 0) {   // lanes 0-7 (node A) and 32-39 (node B) hold fsub 0..7
        float di = dinv[node];
        bf16x8 sv = *(const bf16x8*)(base + (size_t)node * 256);
        acc8p(di * di, sv, acc);
        int feat = chunk * 64 + fsub * 8;
        float4 b0 = *(const float4*)(bias + feat);
        float4 b1 = *(const float4*)(bias + feat + 4);
        acc[0][0] += b0.x; acc[0][1] += b0.y; acc[1][0] += b0.z; acc[1][1] += b0.w;
        acc[2][0] += b1.x; acc[2][1] += b1.y; acc[3][0] += b1.z; acc[3][1] += b1.w;
        if (!FINAL) {
            union { bf16x8 v; ushort s[8]; } o;
            #pragma unroll
            for (int k = 0; k < 8; ++k)
                o.s[k] = f2b(fmaxf(acc[k >> 1][k & 1], 0.f));
            *(bf16x8*)(hb + (size_t)node * 256 + feat) = o.v;
        } else {
            float4 o0 = {acc[0][0], acc[0][1], acc[1][0], acc[1][1]};
            float4 o1 = {acc[2][0], acc[2][1], acc[3][0], acc[3][1]};
            *(float4*)(h3 + (size_t)node * 256 + feat)     = o0;
            *(float4*)(h3 + (size_t)node * 256 + feat + 4) = o1;
            float4 w0 = *(const float4*)(Wout + feat);
            float4 w1 = *(const float4*)(Wout + feat + 4);
            float dot = o0.x * w0.x + o0.y * w0.y + o0.z * w0.z + o0.w * w0.w
                      + o1.x * w1.x + o1.y * w1.y + o1.z * w1.z + o1.w * w1.w;
            #pragma unroll
            for (int d = 1; d < 8; d <<= 1)
                dot += __shfl_xor(dot, d, 64);   // reduce across 8 fsub lanes
            if (fsub == 0) atomicAdd(&outv[node], dot);
        }
    }
}

extern "C" void kernel_launch(void* const* d_in, const int* in_sizes, int n_in,
                              void* d_out, int out_size, void* d_ws, size_t ws_size,
                              hipStream_t stream) {
    const int n = NN, e = EE;
    const float* x    = (const float*)d_in[0];
    const int*   eidx = (const int*)d_in[1];
    const float* W1   = (const float*)d_in[2];
    const float* b1   = (const float*)d_in[3];
    const float* Wh   = (const float*)d_in[4];
    const float* bh   = (const float*)d_in[5];
    const float* W2   = (const float*)d_in[6];
    const float* b2   = (const float*)d_in[7];
    const float* Wout = (const float*)d_in[8];
    const float* bout = (const float*)d_in[9];
    const int* row = eidx;        // sources
    const int* col = eidx + e;    // destinations

    char* ws = (char*)d_ws;
    int*      cnt     = (int*)ws;      ws += (size_t)n * 4;
    int*      offs    = (int*)ws;      ws += (size_t)n * 4;
    int*      cursor  = (int*)ws;      ws += (size_t)n * 4;
    float*    dinv    = (float*)ws;    ws += (size_t)n * 4;
    int*      bsum    = (int*)ws;      ws += (size_t)256 * 4;
    unsigned* pq      = (unsigned*)ws; ws += (size_t)PQ_ALLOC * 4;
    ushort*   xb      = (ushort*)ws;   ws += (size_t)n * 256 * 2;   // bf16 x
    ushort*   hb      = (ushort*)ws;   ws += (size_t)n * 256 * 2;   // bf16 hidden
    ushort*   g2      = (ushort*)ws;   ws += (size_t)n * 256 * 2;   // bf16 GEMM out
    ushort*   wt      = (ushort*)ws;   ws += (size_t)3 * 256 * 512 * 2;
    ushort* wt1 = wt;
    ushort* wt2 = wt + (size_t)256 * 512;
    ushort* wt3 = wt + (size_t)2 * 256 * 512;

    float* outv = (float*)d_out;
    float* h3   = (float*)d_out + n;

    int nb_n = (n + 255) / 256;     // 79
    int nb_e = (e + 255) / 256;

    // prep first: wprep x3 + cvt + init_out + init_cnt + pq zero-fill
    prep_kernel<<<768 + 2500 + 79 + 79 + 1025, 256, 0, stream>>>(
        W1, Wh, W2, wt, x, xb, bout, outv, cnt, pq, n);

    // CSR build (segments padded to x16)
    hist_kernel<<<nb_e, 256, 0, stream>>>(col, cnt, e);
    scan_p1_kernel<<<nb_n, 256, 0, stream>>>(cnt, offs, bsum, dinv, n);
    scan_p23_kernel<<<nb_n, 256, 0, stream>>>(offs, bsum, cursor, n, nb_n);
    scatter_kernel<<<nb_e, 256, 0, stream>>>(row, col, dinv, cursor, pq, e);

    int agrid = (n / 8) * 4;            // 10000 blocks
    dim3 ggrid((n + 127) / 128, 4);     // (157, 4) = 628 blocks

    // layer 1: G1 = xb @ W1'' ; hb = relu(Agg(G1) + b1)
    gemm_mfma_kernel<<<ggrid, 256, 0, stream>>>(xb, wt1, g2, n);
    agg_kernel<false><<<agrid, 256, 0, stream>>>(
        g2, offs, cnt, pq, dinv, b1, hb, nullptr, nullptr, nullptr, n);
    // layer 2
    gemm_mfma_kernel<<<ggrid, 256, 0, stream>>>(hb, wt2, g2, n);
    agg_kernel<false><<<agrid, 256, 0, stream>>>(
        g2, offs, cnt, pq, dinv, bh, hb, nullptr, nullptr, nullptr, n);
    // layer 3: G3 = hb @ W2'' ; h3 = Agg(G3) + b2 (f32, into d_out) + fused decoder
    gemm_mfma_kernel<<<ggrid, 256, 0, stream>>>(hb, wt3, g2, n);
    agg_kernel<true><<<agrid, 256, 0, stream>>>(
        g2, offs, cnt, pq, dinv, b2, nullptr, h3, Wout, outv, n);
}

// Round 20
// 207.898 us; speedup vs baseline: 1.1504x; 1.1504x over previous
//
#include <hip/hip_runtime.h>
#include <hip/hip_bf16.h>

#define NN 20000
#define EE 640000
#define PQ_ALLOC 1049600   // padded CSR capacity (uints): >= E + 15*N + slack; 1025*1024

typedef __attribute__((ext_vector_type(8))) short bf16x8;
typedef __attribute__((ext_vector_type(4))) float f32x4;
typedef __attribute__((ext_vector_type(2))) float f32x2;

__device__ __forceinline__ ushort f2b(float f) {
    __hip_bfloat16 h = __float2bfloat16(f);
    return *(ushort*)&h;
}
__device__ __forceinline__ float b2f(ushort u) {
    __hip_bfloat16 h = *(__hip_bfloat16*)&u;
    return __bfloat162float(h);
}

// accumulate 8 bf16 feats scaled by m into 4 packed f32x2 accs (v_pk_fma_f32)
__device__ __forceinline__ void acc8p(float m, bf16x8 v, f32x2* acc) {
    union { bf16x8 v; unsigned u[4]; } t;
    t.v = v;
    f32x2 mm = {m, m};
    #pragma unroll
    for (int k = 0; k < 4; ++k) {
        f32x2 f = { __uint_as_float(t.u[k] << 16),
                    __uint_as_float(t.u[k] & 0xffff0000u) };
        acc[k] = __builtin_elementwise_fma(mm, f, acc[k]);
    }
}

// async global->LDS, 16B per lane. LDS dest = wave-uniform base + lane*16.
__device__ __forceinline__ void gload16(const ushort* g, ushort* l) {
    __builtin_amdgcn_global_load_lds(
        (const __attribute__((address_space(1))) void*)g,
        (__attribute__((address_space(3))) void*)l, 16, 0, 0);
}

// ---------------- CSR build ----------------

__global__ void hist_kernel(const int* __restrict__ col, int* __restrict__ cnt, int e) {
    int i = blockIdx.x * 256 + threadIdx.x;
    if (i < e) atomicAdd(&cnt[col[i]], 1);
}

__device__ __forceinline__ int block_exscan(int v) {
    __shared__ int wsum[4];
    int tid = threadIdx.x, lane = tid & 63, w = tid >> 6;
    int x = v;
    #pragma unroll
    for (int d = 1; d < 64; d <<= 1) {
        int y = __shfl_up(x, d, 64);
        if (lane >= d) x += y;
    }
    if (lane == 63) wsum[w] = x;
    __syncthreads();
    if (tid == 0) {
        int s = 0;
        #pragma unroll
        for (int k = 0; k < 4; ++k) { int t = wsum[k]; wsum[k] = s; s += t; }
    }
    __syncthreads();
    return wsum[w] + x - v;
}

// scan phase 1 (over counts PADDED to x16) + dinv fused
__global__ __launch_bounds__(256) void scan_p1_kernel(const int* __restrict__ cnt,
                                                      int* __restrict__ offs,
                                                      int* __restrict__ bsum,
                                                      float* __restrict__ dinv, int n) {
    int i = blockIdx.x * 256 + threadIdx.x;
    int v = (i < n) ? cnt[i] : 0;
    int vpad = (v + 15) & ~15;
    int e = block_exscan(vpad);
    if (i < n) {
        offs[i] = e;
        dinv[i] = rsqrtf((float)(v + 1));   // +1 self-loop; always > 0
    }
    if (threadIdx.x == 255) bsum[blockIdx.x] = e + vpad;
}

// merged phases 2+3: each block locally scans bsum (nblk <= 256) and applies its base
__global__ __launch_bounds__(256) void scan_p23_kernel(int* __restrict__ offs,
                                                       const int* __restrict__ bsum,
                                                       int* __restrict__ cursor,
                                                       int n, int nblk) {
    __shared__ int base_s;
    int t = threadIdx.x;
    int v = (t < nblk) ? bsum[t] : 0;
    int e = block_exscan(v);
    if (t == blockIdx.x) base_s = e;
    __syncthreads();
    int i = blockIdx.x * 256 + t;
    if (i < n) {
        int o = offs[i] + base_s;
        offs[i] = o;
        cursor[i] = o;
    }
}

// pack: hi16 = bf16(norm), lo16 = src id (n < 65536). Pad slots stay 0 (pre-zeroed).
__global__ void scatter_kernel(const int* __restrict__ row, const int* __restrict__ col,
                               const float* __restrict__ dinv, int* __restrict__ cursor,
                               unsigned* __restrict__ pq, int e) {
    int i = blockIdx.x * 256 + threadIdx.x;
    if (i >= e) return;
    int s = row[i], d = col[i];
    int pos = atomicAdd(&cursor[d], 1);
    unsigned nb = f2b(dinv[s] * dinv[d]);
    pq[pos] = (nb << 16) | (unsigned)s;
}

// ---------------- fused prep: wprep x3 + x->bf16 + out=bout + cnt=0 + pq=0 ----------------
__global__ __launch_bounds__(256) void prep_kernel(
    const float* __restrict__ W1, const float* __restrict__ Wh,
    const float* __restrict__ W2, ushort* __restrict__ Wt,
    const float* __restrict__ x, ushort* __restrict__ xb,
    const float* __restrict__ bout, float* __restrict__ outv,
    int* __restrict__ cnt, unsigned* __restrict__ pq, int n) {
    int bid = blockIdx.x;
    if (bid < 768) {
        const float* W = (bid < 256) ? W1 : ((bid < 512) ? Wh : W2);
        ushort* dst = Wt + (size_t)(bid >> 8) * 256 * 512;
        int col = bid & 255;
        #pragma unroll
        for (int kv = threadIdx.x; kv < 512; kv += 256) {
            int k = kv & 255;
            float w = W[(size_t)k * 256 + col];
            ushort hi = f2b(w);
            dst[(size_t)col * 512 + kv] = (kv < 256) ? hi : f2b(w - b2f(hi));
        }
    } else if (bid < 768 + 2500) {
        int i = (bid - 768) * 256 + threadIdx.x;   // per 8 elems, total n*32
        if (i < n * 32) {
            float4 a = ((const float4*)x)[2 * i];
            float4 b = ((const float4*)x)[2 * i + 1];
            union { bf16x8 v; ushort s[8]; } o;
            o.s[0] = f2b(a.x); o.s[1] = f2b(a.y); o.s[2] = f2b(a.z); o.s[3] = f2b(a.w);
            o.s[4] = f2b(b.x); o.s[5] = f2b(b.y); o.s[6] = f2b(b.z); o.s[7] = f2b(b.w);
            ((bf16x8*)xb)[i] = o.v;
        }
    } else if (bid < 768 + 2500 + 79) {
        int i = (bid - 3268) * 256 + threadIdx.x;
        if (i < n) outv[i] = bout[0];
    } else if (bid < 768 + 2500 + 79 + 79) {
        int i = (bid - 3347) * 256 + threadIdx.x;
        if (i < n) cnt[i] = 0;
    } else {
        int i = (bid - 3426) * 256 + threadIdx.x;   // uint4 zero-fill of pq
        uint4 z = {0u, 0u, 0u, 0u};
        ((uint4*)pq)[i] = z;                        // PQ_ALLOC/4 = 1025*256
    }
}

// ---------------- bf16 MFMA GEMM: G = A @ (W_hi + W_lo), real K=256, 4 kt ----------------
// Per kt: stage A (128x64) ONCE + B tile (128 rows: 0-63 = W_hi cols, 64-127 = W_lo cols).
// Each af used against both bf_hi and bf_lo into the same acc. LDS dbuf, vmcnt(8), XOR-swizzle.
__global__ __launch_bounds__(256) void gemm_mfma_kernel(
    const ushort* __restrict__ A, const ushort* __restrict__ Wt,
    ushort* __restrict__ G, int n) {
    __shared__ ushort Ast[2][128][64];
    __shared__ ushort Bst[2][128][64];
    int tid = threadIdx.x;
    int lane = tid & 63, wid = tid >> 6;
    int rowbase = blockIdx.x * 128;
    int colbase = blockIdx.y * 64;

    f32x4 zero = {0.f, 0.f, 0.f, 0.f};
    f32x4 acc[2][4];
    #pragma unroll
    for (int m = 0; m < 2; ++m)
        #pragma unroll
        for (int nn = 0; nn < 4; ++nn) acc[m][nn] = zero;

    int rsub = lane >> 3, sl = lane & 7;
    const ushort* asrc[4];
    const ushort* bsrc[4];
    #pragma unroll
    for (int q = 0; q < 4; ++q) {
        int rin = wid * 32 + q * 8 + rsub;      // 0..127
        int c = sl ^ (rin & 7);
        int gr = min(rowbase + rin, n - 1);
        asrc[q] = A + (size_t)gr * 256 + c * 8;
        int col_r = rin & 63;
        int part = rin >> 6;                    // 0 = hi, 1 = lo
        bsrc[q] = Wt + (size_t)(colbase + col_r) * 512 + part * 256 + c * 8;
    }

    auto stage = [&](int kt, int buf) {
        int kv0 = kt * 64;
        #pragma unroll
        for (int q = 0; q < 4; ++q)
            gload16(asrc[q] + kv0, &Ast[buf][wid * 32 + q * 8][0]);
        #pragma unroll
        for (int q = 0; q < 4; ++q)
            gload16(bsrc[q] + kv0, &Bst[buf][wid * 32 + q * 8][0]);
    };

    stage(0, 0);
    for (int kt = 0; kt < 4; ++kt) {
        int cur = kt & 1;
        if (kt < 3) {
            stage(kt + 1, cur ^ 1);
            asm volatile("s_waitcnt vmcnt(8)" ::: "memory");
        } else {
            asm volatile("s_waitcnt vmcnt(0)" ::: "memory");
        }
        __builtin_amdgcn_s_barrier();
        #pragma unroll
        for (int kk = 0; kk < 2; ++kk) {
            int clog = kk * 4 + (lane >> 4);
            bf16x8 af[2], bfh[4], bfl[4];
            #pragma unroll
            for (int m = 0; m < 2; ++m) {
                int row = wid * 32 + m * 16 + (lane & 15);
                af[m] = *(const bf16x8*)&Ast[cur][row][(clog ^ (row & 7)) * 8];
            }
            #pragma unroll
            for (int nn = 0; nn < 4; ++nn) {
                int rowh = nn * 16 + (lane & 15);
                int rowl = rowh + 64;
                bfh[nn] = *(const bf16x8*)&Bst[cur][rowh][(clog ^ (rowh & 7)) * 8];
                bfl[nn] = *(const bf16x8*)&Bst[cur][rowl][(clog ^ (rowl & 7)) * 8];
            }
            #pragma unroll
            for (int m = 0; m < 2; ++m)
                #pragma unroll
                for (int nn = 0; nn < 4; ++nn) {
                    acc[m][nn] = __builtin_amdgcn_mfma_f32_16x16x32_bf16(
                        af[m], bfh[nn], acc[m][nn], 0, 0, 0);
                    acc[m][nn] = __builtin_amdgcn_mfma_f32_16x16x32_bf16(
                        af[m], bfl[nn], acc[m][nn], 0, 0, 0);
                }
        }
        __builtin_amdgcn_s_barrier();
    }

    #pragma unroll
    for (int nn = 0; nn < 4; ++nn) {
        int col = colbase + nn * 16 + (lane & 15);
        #pragma unroll
        for (int m = 0; m < 2; ++m) {
            int grow0 = rowbase + wid * 32 + m * 16 + ((lane >> 4) << 2);
            f32x4 v = acc[m][nn];
            #pragma unroll
            for (int rr = 0; rr < 4; ++rr) {
                int row = grow0 + rr;
                if (row < n)
                    G[(size_t)row * 256 + col] = f2b(v[rr]);
            }
        }
    }
}

// ---------------- aggregation v13: padded CSR -> predication-free loop ----------------
// G bf16 [n][256]. chunk = bid&3 (slice 2.56MB, XCD-pinned). 4 waves x 2 nodes = 8 nodes/block.
// Lane: half = lane>>5 (node), esub = (lane>>3)&3 (4 edge slots), fsub = lane&7 (bf16x8).
// Segments padded to x16 with (norm=0, src=0) -> no compares/selects in the loop.
template<bool FINAL>
__global__ __launch_bounds__(256) void agg_kernel(
    const ushort* __restrict__ g,
    const int* __restrict__ offs, const int* __restrict__ cnt,
    const unsigned* __restrict__ pq,
    const float* __restrict__ dinv,
    const float* __restrict__ bias,
    ushort* __restrict__ hb,          // !FINAL
    float* __restrict__ h3,           // FINAL
    const float* __restrict__ Wout, float* __restrict__ outv,
    int n) {
    int chunk = blockIdx.x & 3;
    int lane = threadIdx.x & 63;
    int half = lane >> 5;
    int esub = (lane >> 3) & 3;
    int fsub = lane & 7;
    int node = (blockIdx.x >> 2) * 8 + (threadIdx.x >> 6) * 2 + half;  // n%8==0
    const ushort* base = g + chunk * 64 + fsub * 8;

    int beg = offs[node];
    int npad = (cnt[node] + 15) & ~15;
    const unsigned* pe = pq + beg + esub;
    f32x2 acc[4] = {};

    unsigned q0 = pe[0], q1 = pe[4], q2 = pe[8], q3 = pe[12];

    for (int j = 0; j < npad; j += 16) {
        const unsigned* pn = pe + j + 16;      // prefetch (may overrun segment; never consumed)
        unsigned p0 = pn[0], p1 = pn[4], p2 = pn[8], p3 = pn[12];

        float m0 = __uint_as_float(q0 & 0xffff0000u);
        float m1 = __uint_as_float(q1 & 0xffff0000u);
        float m2 = __uint_as_float(q2 & 0xffff0000u);
        float m3 = __uint_as_float(q3 & 0xffff0000u);
        bf16x8 v0 = *(const bf16x8*)(base + (size_t)(q0 & 0xffffu) * 256);
        bf16x8 v1 = *(const bf16x8*)(base + (size_t)(q1 & 0xffffu) * 256);
        bf16x8 v2 = *(const bf16x8*)(base + (size_t)(q2 & 0xffffu) * 256);
        bf16x8 v3 = *(const bf16x8*)(base + (size_t)(q3 & 0xffffu) * 256);
        acc8p(m0, v0, acc);
        acc8p(m1, v1, acc);
        acc8p(m2, v2, acc);
        acc8p(m3, v3, acc);
        q0 = p0; q1 = p1; q2 = p2; q3 = p3;
    }

    // reduce across the 4 esub groups within each 32-lane half
    #pragma unroll
    for (int d = 8; d < 32; d <<= 1)
        #pragma unroll
        for (int k = 0; k < 4; ++k) {
            acc[k][0] += __shfl_xor(acc[k][0], d, 64);
            acc[k][1] += __shfl_xor(acc[k][1], d, 64);
        }

    if (esub == 0) {   // lanes 0-7 (node A) and 32-39 (node B) hold fsub 0..7
        float di = dinv[node];
        bf16x8 sv = *(const bf16x8*)(base + (size_t)node * 256);
        acc8p(di * di, sv, acc);
        int feat = chunk * 64 + fsub * 8;
        float4 b0 = *(const float4*)(bias + feat);
        float4 b1 = *(const float4*)(bias + feat + 4);
        acc[0][0] += b0.x; acc[0][1] += b0.y; acc[1][0] += b0.z; acc[1][1] += b0.w;
        acc[2][0] += b1.x; acc[2][1] += b1.y; acc[3][0] += b1.z; acc[3][1] += b1.w;
        if (!FINAL) {
            union { bf16x8 v; ushort s[8]; } o;
            #pragma unroll
            for (int k = 0; k < 8; ++k)
                o.s[k] = f2b(fmaxf(acc[k >> 1][k & 1], 0.f));
            *(bf16x8*)(hb + (size_t)node * 256 + feat) = o.v;
        } else {
            float4 o0 = {acc[0][0], acc[0][1], acc[1][0], acc[1][1]};
            float4 o1 = {acc[2][0], acc[2][1], acc[3][0], acc[3][1]};
            *(float4*)(h3 + (size_t)node * 256 + feat)     = o0;
            *(float4*)(h3 + (size_t)node * 256 + feat + 4) = o1;
            float4 w0 = *(const float4*)(Wout + feat);
            float4 w1 = *(const float4*)(Wout + feat + 4);
            float dot = o0.x * w0.x + o0.y * w0.y + o0.z * w0.z + o0.w * w0.w
                      + o1.x * w1.x + o1.y * w1.y + o1.z * w1.z + o1.w * w1.w;
            #pragma unroll
            for (int d = 1; d < 8; d <<= 1)
                dot += __shfl_xor(dot, d, 64);   // reduce across 8 fsub lanes
            if (fsub == 0) atomicAdd(&outv[node], dot);
        }
    }
}

extern "C" void kernel_launch(void* const* d_in, const int* in_sizes, int n_in,
                              void* d_out, int out_size, void* d_ws, size_t ws_size,
                              hipStream_t stream) {
    const int n = NN, e = EE;
    const float* x    = (const float*)d_in[0];
    const int*   eidx = (const int*)d_in[1];
    const float* W1   = (const float*)d_in[2];
    const float* b1   = (const float*)d_in[3];
    const float* Wh   = (const float*)d_in[4];
    const float* bh   = (const float*)d_in[5];
    const float* W2   = (const float*)d_in[6];
    const float* b2   = (const float*)d_in[7];
    const float* Wout = (const float*)d_in[8];
    const float* bout = (const float*)d_in[9];
    const int* row = eidx;        // sources
    const int* col = eidx + e;    // destinations

    char* ws = (char*)d_ws;
    int*      cnt     = (int*)ws;      ws += (size_t)n * 4;
    int*      offs    = (int*)ws;      ws += (size_t)n * 4;
    int*      cursor  = (int*)ws;      ws += (size_t)n * 4;
    float*    dinv    = (float*)ws;    ws += (size_t)n * 4;
    int*      bsum    = (int*)ws;      ws += (size_t)256 * 4;
    unsigned* pq      = (unsigned*)ws; ws += (size_t)PQ_ALLOC * 4;
    ushort*   xb      = (ushort*)ws;   ws += (size_t)n * 256 * 2;   // bf16 x
    ushort*   hb      = (ushort*)ws;   ws += (size_t)n * 256 * 2;   // bf16 hidden
    ushort*   g2      = (ushort*)ws;   ws += (size_t)n * 256 * 2;   // bf16 GEMM out
    ushort*   wt      = (ushort*)ws;   ws += (size_t)3 * 256 * 512 * 2;
    ushort* wt1 = wt;
    ushort* wt2 = wt + (size_t)256 * 512;
    ushort* wt3 = wt + (size_t)2 * 256 * 512;

    float* outv = (float*)d_out;
    float* h3   = (float*)d_out + n;

    int nb_n = (n + 255) / 256;     // 79
    int nb_e = (e + 255) / 256;

    // prep first: wprep x3 + cvt + init_out + init_cnt + pq zero-fill
    prep_kernel<<<768 + 2500 + 79 + 79 + 1025, 256, 0, stream>>>(
        W1, Wh, W2, wt, x, xb, bout, outv, cnt, pq, n);

    // CSR build (segments padded to x16)
    hist_kernel<<<nb_e, 256, 0, stream>>>(col, cnt, e);
    scan_p1_kernel<<<nb_n, 256, 0, stream>>>(cnt, offs, bsum, dinv, n);
    scan_p23_kernel<<<nb_n, 256, 0, stream>>>(offs, bsum, cursor, n, nb_n);
    scatter_kernel<<<nb_e, 256, 0, stream>>>(row, col, dinv, cursor, pq, e);

    int agrid = (n / 8) * 4;            // 10000 blocks
    dim3 ggrid((n + 127) / 128, 4);     // (157, 4) = 628 blocks

    // layer 1: G1 = xb @ W1'' ; hb = relu(Agg(G1) + b1)
    gemm_mfma_kernel<<<ggrid, 256, 0, stream>>>(xb, wt1, g2, n);
    agg_kernel<false><<<agrid, 256, 0, stream>>>(
        g2, offs, cnt, pq, dinv, b1, hb, nullptr, nullptr, nullptr, n);
    // layer 2
    gemm_mfma_kernel<<<ggrid, 256, 0, stream>>>(hb, wt2, g2, n);
    agg_kernel<false><<<agrid, 256, 0, stream>>>(
        g2, offs, cnt, pq, dinv, bh, hb, nullptr, nullptr, nullptr, n);
    // layer 3: G3 = hb @ W2'' ; h3 = Agg(G3) + b2 (f32, into d_out) + fused decoder
    gemm_mfma_kernel<<<ggrid, 256, 0, stream>>>(hb, wt3, g2, n);
    agg_kernel<true><<<agrid, 256, 0, stream>>>(
        g2, offs, cnt, pq, dinv, b2, nullptr, h3, Wout, outv, n);
}